// Round 15
// baseline (97.145 us; speedup 1.0000x reference)
//
#include <hip/hip_runtime.h>
#include <hip/hip_fp16.h>
#include <math.h>

// ---- nearest-neighbor LUT: 8192 floats over d in [-0.2, 1.27456), h=1.8e-4 ----
// BYTE index = (v*psc + psh - LO - theta) * INVH4, clamped to [0, 32764].
// f == 0 (to ~1e-10) outside the band -> clamped lanes read edge cells (~0)
// and broadcast; per-lane clamp limit encodes border validity.
#define NLUT    8192
#define LUT_LO  (-0.2)
#define LUT_H   (1.8e-4)
#define INVH4   22222.222222222f   // 4/LUT_H (byte-scaled)
#define BLIM    32764.0f           // (NLUT-1)*4
#define BAND_LO (-0.35f)
#define BAND_HI (1.28f)
// static conservative theta2 window (theta2 ~ U[2.8,4.8] by problem spec)
#define WLO     (2.8f + BAND_LO)   // 2.45
#define WHI     (4.8f + BAND_HI)   // 6.08

// ---- ws layout (bytes) ----
#define WS_LUT    0          // float[8192]     32768
#define WS_TH2T   32768      // float[36864]    147456 -> 180224
#define WS_TH1S   180224     // float[36864]    147456 -> 327680
#define WS_C2H    327680     // __half[262144]  524288 -> 851968
#define WS_MASK   851968     // u64[4096]       32768  -> 884736 (ZEROED in k0)
#define WS_SUMS1  884736     // float[128]      512    -> 885248
#define WS_SUMS2  885248     // float[128]      512    -> 885760
#define WS_TOTAL  885760
#define ZERO_BYTES (WS_TOTAL - WS_MASK)   // 33792 = 8448 words -> 33 blocks

__device__ __forceinline__ float f_exact32(float d) {
    const float inv_nvt = (float)(1.0 / (1.5 * 0.026));
    float a1 = fminf(fmaxf(d * inv_nvt, -30.f), 30.f);
    float a2 = fminf(fmaxf((d - 0.1f) * inv_nvt, -30.f), 30.f);
    float s1 = log1pf(expf(a1));
    float s2 = log1pf(expf(a2));
    return 0.0005625f * (s1 * s1 - s2 * s2);
}

// K0: blk<32 LUT | <41 th2t LDS-tiled transpose | <185 th1s | <218 zero
__global__ __launch_bounds__(256) void k0_prep(
    const float* __restrict__ theta1, const float* __restrict__ theta2,
    const float* __restrict__ psh,
    float* __restrict__ lutg, float* __restrict__ th2t,
    float* __restrict__ th1s, unsigned* __restrict__ zerow)
{
    int blk = blockIdx.x, tid = threadIdx.x;
    if (blk < 32) {
        int i = blk * 256 + tid;                       // 0..8191
        float d = (float)LUT_LO + ((float)i + 0.5f) * (float)LUT_H;
        lutg[i] = f_exact32(d);
    } else if (blk < 41) {
        // th2t transpose, one 64k x 64p tile per block; both sides coalesced
        __shared__ float tile[64][65];
        int kbase = (blk - 32) * 64;
        int kk = tid & 63, pp = tid >> 6;              // read: lane = k
        #pragma unroll
        for (int i = 0; i < 16; ++i) {
            int p = pp * 16 + i;
            tile[p][kk] = theta2[p * 576 + kbase + kk];
        }
        __syncthreads();
        int p2 = tid & 63, kr = tid >> 6;              // write: lane = p
        #pragma unroll
        for (int i = 0; i < 16; ++i) {
            int k = kr * 16 + i;
            th2t[(kbase + k) * 64 + p2] = tile[p2][k];
        }
    } else if (blk < 185) {
        int i = (blk - 41) * 256 + tid;                // 0..36863 (p-major [p][k])
        // byte-index term: (psh - LO - theta1) * INVH4 ; x term added in k1
        th1s[i] = (psh[0] - (float)LUT_LO - theta1[i]) * INVH4;
    } else {
        int i = (blk - 185) * 256 + tid;               // 0..8447
        if (i < (int)(ZERO_BYTES / 4)) zerow[i] = 0u;  // masks + sums1 + sums2
    }
}

// K1: dense conv1 (measured-best R6/R14 structure; only change vs R14: c-loop
// unroll 2 -> 4 to widen the scheduler's independent-op window). grid 1024 =
// b(4) x yp(16) x pq(16); block = 512 = 8 waves: wave w -> plane pq*4 + (w&3),
// c-half (w>>2); 4 blocks/CU -> 32 waves/CU (HW cap). Raw-x coalesced f32
// loads, wave-uniform pre-scaled theta -> s_loads, unconditional clamped LUT
// gathers (border folded into per-lane clamp limit). Two parity accumulators.
__global__ __launch_bounds__(512, 8) void k1_conv1(
    const float* __restrict__ x, const float* __restrict__ th1s,
    const float* __restrict__ psc, const float* __restrict__ ls1,
    const float* __restrict__ lutg,
    float* __restrict__ rawb, float* __restrict__ sums1)
{
    __shared__ float lut[NLUT];
    __shared__ float part[256];
    {
        const float4* s = (const float4*)lutg;
        float4* d = (float4*)lut;
        for (int i = threadIdx.x; i < NLUT / 4; i += 512) d[i] = s[i];
    }
    __syncthreads();

    int blk = blockIdx.x;
    int pq = blk & 15;
    int yp = (blk >> 4) & 15;
    int b  = blk >> 8;
    int wv   = __builtin_amdgcn_readfirstlane((int)threadIdx.x >> 6);
    int lane = threadIdx.x & 63;
    int r = lane >> 5, xc = lane & 31;
    int y = yp * 2 + r;
    int p  = pq * 4 + (wv & 3);
    int c0 = (wv >> 2) * 32;

    // per-lane tap offsets (address-clamped) + clamp limit encoding validity
    int poff[9]; float lim[9];
    #pragma unroll
    for (int t = 0; t < 9; ++t) {
        int ny = y + t / 3 - 1, nx = xc + t % 3 - 1;
        bool val = ((unsigned)ny < 32u) && ((unsigned)nx < 32u);
        int nyc = min(max(ny, 0), 31), nxc = min(max(nx, 0), 31);
        poff[t] = nyc * 32 + nxc;
        lim[t] = val ? BLIM : 0.0f;
    }

    const float* xb = x + b * 65536 + c0 * 1024;
    const float* tp = th1s + p * 576 + c0 * 9;
    float SC = psc[0] * INVH4;
    float acc0 = 0.f, acc1 = 0.f;

    #pragma unroll 4
    for (int c = 0; c < 32; ++c) {
        const float* xr = xb + c * 1024;
        float v[9];
        #pragma unroll
        for (int t = 0; t < 9; ++t) v[t] = xr[poff[t]];
        const float* tc = tp + c * 9;
        #pragma unroll
        for (int t = 0; t < 9; ++t) {
            float q = fmaf(v[t], SC, tc[t]);         // theta via SGPR
            q = fminf(fmaxf(q, 0.f), lim[t]);        // v_med3 (border folded)
            int qb = (int)q & ~3;                    // aligned byte offset
            float e = *(const float*)((const char*)lut + qb);
            if (t & 1) acc1 += e; else acc0 += e;
        }
    }
    float acc = acc0 + acc1;

    // combine c-halves: upper half deposits, lower half finalizes
    if (wv >= 4) part[(wv & 3) * 64 + lane] = acc;
    __syncthreads();
    if (wv < 4) {
        acc += part[wv * 64 + lane];
        float r0 = ls1[0] * acc;
        rawb[((b * 64 + p) * 32 + y) * 32 + xc] = r0;

        float s0 = r0, q0 = r0 * r0;
        for (int s = 32; s > 0; s >>= 1) {
            s0 += __shfl_xor(s0, s);
            q0 += __shfl_xor(q0, s);
        }
        if (lane == 0) {
            atomicAdd(&sums1[p], s0);
            atomicAdd(&sums1[64 + p], q0);
        }
    }
}

// K3: BN1 apply in place on rawb (=d_out) + activity masks via atomicOr (masks
// region zeroed by k0). float4.
__global__ __launch_bounds__(256) void k3_bn1mask(float* __restrict__ v2,
    const float* __restrict__ sums1, const float* __restrict__ g1,
    const float* __restrict__ b1, unsigned long long* __restrict__ masks)
{
    int i4 = blockIdx.x * 256 + threadIdx.x;       // 0..65535
    int idx = i4 * 4;
    int c = (idx >> 10) & 63;
    int b = idx >> 16;
    float m   = sums1[c] * (1.f / 4096.f);
    float var = sums1[64 + c] * (1.f / 4096.f) - m * m;
    var = fmaxf(var, 0.f);
    float rstd = rsqrtf(var + 1e-5f);
    float sc = rstd * g1[c];
    float sh = b1[c] - m * sc;
    float4 v = ((float4*)v2)[i4];
    v.x = fmaf(v.x, sc, sh); v.y = fmaf(v.y, sc, sh);
    v.z = fmaf(v.z, sc, sh); v.w = fmaf(v.w, sc, sh);
    ((float4*)v2)[i4] = v;
    unsigned long long bit = 1ull << c;
    float vv[4] = {v.x, v.y, v.z, v.w};
    #pragma unroll
    for (int k = 0; k < 4; ++k) {
        if (vv[k] > WLO && vv[k] < WHI)
            atomicOr(&masks[b * 1024 + ((idx + k) & 1023)], bit);
    }
}

// K4: sparse conv2. grid 1024, wave per pixel, lane = output plane. Exact f32 eval.
__global__ __launch_bounds__(256) void k4_conv2(const float* __restrict__ v2,
    const float* __restrict__ th2t, const unsigned long long* __restrict__ masks,
    const float* __restrict__ ls2, __half* __restrict__ c2h, float* __restrict__ sums2)
{
    int wv = __builtin_amdgcn_readfirstlane((int)threadIdx.x >> 6);
    int lane = threadIdx.x & 63;
    int P = blockIdx.x * 4 + wv;                   // 0..4095
    int b = P >> 10, rem = P & 1023;
    int y = rem >> 5, xq2 = rem & 31;
    float l2 = ls2[0];
    const float inv_nvt = (float)(1.0 / (1.5 * 0.026));
    float acc = 0.f;

    #pragma unroll
    for (int j = 0; j < 9; ++j) {
        int ny = y + j / 3 - 1, nx = xq2 + j % 3 - 1;
        if ((unsigned)ny < 32u && (unsigned)nx < 32u) {
            int tp = ny * 32 + nx;
            unsigned long long mk = masks[b * 1024 + tp];
            while (mk) {
                int c = __ffsll((long long)mk) - 1;
                mk &= mk - 1;
                float v  = v2[(b * 64 + c) * 1024 + tp];            // uniform
                float th = th2t[(c * 9 + j) * 64 + lane];           // coalesced
                float d = v - th;
                if (d > BAND_LO && d < BAND_HI) {
                    float a1 = fminf(fmaxf(d * inv_nvt, -30.f), 30.f);
                    float a2 = fminf(fmaxf((d - 0.1f) * inv_nvt, -30.f), 30.f);
                    float s1 = __logf(1.f + __expf(a1));
                    float s2 = __logf(1.f + __expf(a2));
                    acc += (s1 * s1 - s2 * s2);
                }
            }
        }
    }
    float r2 = 0.0005625f * l2 * acc;
    c2h[((b * 64 + lane) * 32 + y) * 32 + xq2] = __float2half(r2); // channel-major

    __shared__ float ss[256], sq[256];
    ss[threadIdx.x] = r2; sq[threadIdx.x] = r2 * r2;
    __syncthreads();
    if (threadIdx.x < 64) {
        float a  = ss[threadIdx.x] + ss[threadIdx.x + 64] + ss[threadIdx.x + 128] + ss[threadIdx.x + 192];
        float qq = sq[threadIdx.x] + sq[threadIdx.x + 64] + sq[threadIdx.x + 128] + sq[threadIdx.x + 192];
        atomicAdd(&sums2[threadIdx.x], a);
        atomicAdd(&sums2[64 + threadIdx.x], qq);
    }
}

// K6: BN2 apply + residual, c2h -> d_out. float4 on x/out, half2 on c2.
__global__ __launch_bounds__(256) void k6_final(float* __restrict__ out,
    const float* __restrict__ x, const __half* __restrict__ c2h,
    const float* __restrict__ sums2,
    const float* __restrict__ g2, const float* __restrict__ b2)
{
    int i4 = blockIdx.x * 256 + threadIdx.x;       // 0..65535
    int idx = i4 * 4;
    int p = (idx >> 10) & 63;
    float m   = sums2[p] * (1.f / 4096.f);
    float var = sums2[64 + p] * (1.f / 4096.f) - m * m;
    var = fmaxf(var, 0.f);
    float rstd = rsqrtf(var + 1e-5f);
    float sc = rstd * g2[p];
    float sh = b2[p] - m * sc;
    const __half2* ch = (const __half2*)c2h;
    __half2 h0 = ch[i4 * 2], h1 = ch[i4 * 2 + 1];
    float2 c01 = __half22float2(h0), c23 = __half22float2(h1);
    float4 xv = ((const float4*)x)[i4];
    float4 o;
    o.x = fmaf(c01.x, sc, sh) + xv.x;
    o.y = fmaf(c01.y, sc, sh) + xv.y;
    o.z = fmaf(c23.x, sc, sh) + xv.z;
    o.w = fmaf(c23.y, sc, sh) + xv.w;
    ((float4*)out)[i4] = o;
}

extern "C" void kernel_launch(void* const* d_in, const int* in_sizes, int n_in,
                              void* d_out, int out_size, void* d_ws, size_t ws_size,
                              hipStream_t stream)
{
    const float* x   = (const float*)d_in[0];
    const float* th1 = (const float*)d_in[1];
    const float* th2 = (const float*)d_in[2];
    const float* psc = (const float*)d_in[3];
    const float* psh = (const float*)d_in[4];
    const float* l1  = (const float*)d_in[5];
    const float* l2  = (const float*)d_in[6];
    const float* g1  = (const float*)d_in[7];
    const float* b1  = (const float*)d_in[8];
    const float* g2  = (const float*)d_in[9];
    const float* b2  = (const float*)d_in[10];
    float* out = (float*)d_out;
    char* ws = (char*)d_ws;
    if (ws_size < (size_t)WS_TOTAL) return;  // defensive: leave output poisoned

    float*  lutg = (float*)(ws + WS_LUT);
    float*  th2t = (float*)(ws + WS_TH2T);
    float*  th1s = (float*)(ws + WS_TH1S);
    __half* c2h  = (__half*)(ws + WS_C2H);
    unsigned long long* masks = (unsigned long long*)(ws + WS_MASK);  // zeroed by k0
    float*  sums1 = (float*)(ws + WS_SUMS1);
    float*  sums2 = (float*)(ws + WS_SUMS2);
    unsigned* zerow = (unsigned*)(ws + WS_MASK);  // zero phase covers masks+sums

    float* rawb = out;   // conv1 raw / BN1-applied activations live in d_out

    k0_prep   <<<218,  256, 0, stream>>>(th1, th2, psh, lutg, th2t, th1s, zerow);
    k1_conv1  <<<1024, 512, 0, stream>>>(x, th1s, psc, l1, lutg, rawb, sums1);
    k3_bn1mask<<<256,  256, 0, stream>>>(rawb, sums1, g1, b1, masks);
    k4_conv2  <<<1024, 256, 0, stream>>>(rawb, th2t, masks, l2, c2h, sums2);
    k6_final  <<<256,  256, 0, stream>>>(out, x, c2h, sums2, g2, b2);
}

// Round 16
// 80.125 us; speedup vs baseline: 1.2124x; 1.2124x over previous
//
#include <hip/hip_runtime.h>
#include <hip/hip_fp16.h>
#include <math.h>

// ---- nearest-neighbor LUT: 8192 floats over d in [-0.2, 1.27456), h=1.8e-4 ----
// BYTE index = (v*psc + psh - LO - theta) * INVH4, clamped to [0, 32764].
// f == 0 (to ~1e-10) outside the band -> clamped lanes read edge cells (~0)
// and broadcast; per-lane clamp limit encodes border validity.
#define NLUT    8192
#define LUT_LO  (-0.2)
#define LUT_H   (1.8e-4)
#define INVH4   22222.222222222f   // 4/LUT_H (byte-scaled)
#define BLIM    32764.0f           // (NLUT-1)*4
#define BAND_LO (-0.35f)
#define BAND_HI (1.28f)
// static conservative theta2 window (theta2 ~ U[2.8,4.8] by problem spec)
#define WLO     (2.8f + BAND_LO)   // 2.45
#define WHI     (4.8f + BAND_HI)   // 6.08

// ---- ws layout (bytes) ----
#define WS_LUT    0          // float[8192]     32768
#define WS_TH2T   32768      // float[36864]    147456 -> 180224
#define WS_TH1S   180224     // float[36864]    147456 -> 327680
#define WS_C2H    327680     // __half[262144]  524288 -> 851968
#define WS_MASK   851968     // u64[4096]       32768  -> 884736 (ZEROED in k0)
#define WS_SUMS1  884736     // float[128]      512    -> 885248
#define WS_SUMS2  885248     // float[128]      512    -> 885760
#define WS_TOTAL  885760
#define ZERO_BYTES (WS_TOTAL - WS_MASK)   // 33792 = 8448 words -> 33 blocks

__device__ __forceinline__ float f_exact32(float d) {
    const float inv_nvt = (float)(1.0 / (1.5 * 0.026));
    float a1 = fminf(fmaxf(d * inv_nvt, -30.f), 30.f);
    float a2 = fminf(fmaxf((d - 0.1f) * inv_nvt, -30.f), 30.f);
    float s1 = log1pf(expf(a1));
    float s2 = log1pf(expf(a2));
    return 0.0005625f * (s1 * s1 - s2 * s2);
}

// K0: blk<32 LUT | <41 th2t LDS-tiled transpose | <185 th1s | <218 zero
__global__ __launch_bounds__(256) void k0_prep(
    const float* __restrict__ theta1, const float* __restrict__ theta2,
    const float* __restrict__ psh,
    float* __restrict__ lutg, float* __restrict__ th2t,
    float* __restrict__ th1s, unsigned* __restrict__ zerow)
{
    int blk = blockIdx.x, tid = threadIdx.x;
    if (blk < 32) {
        int i = blk * 256 + tid;                       // 0..8191
        float d = (float)LUT_LO + ((float)i + 0.5f) * (float)LUT_H;
        lutg[i] = f_exact32(d);
    } else if (blk < 41) {
        // th2t transpose, one 64k x 64p tile per block; both sides coalesced
        __shared__ float tile[64][65];
        int kbase = (blk - 32) * 64;
        int kk = tid & 63, pp = tid >> 6;              // read: lane = k
        #pragma unroll
        for (int i = 0; i < 16; ++i) {
            int p = pp * 16 + i;
            tile[p][kk] = theta2[p * 576 + kbase + kk];
        }
        __syncthreads();
        int p2 = tid & 63, kr = tid >> 6;              // write: lane = p
        #pragma unroll
        for (int i = 0; i < 16; ++i) {
            int k = kr * 16 + i;
            th2t[(kbase + k) * 64 + p2] = tile[p2][k];
        }
    } else if (blk < 185) {
        int i = (blk - 41) * 256 + tid;                // 0..36863 (p-major [p][k])
        // byte-index term: (psh - LO - theta1) * INVH4 ; x term added in k1
        th1s[i] = (psh[0] - (float)LUT_LO - theta1[i]) * INVH4;
    } else {
        int i = (blk - 185) * 256 + tid;               // 0..8447
        if (i < (int)(ZERO_BYTES / 4)) zerow[i] = 0u;  // masks + sums1 + sums2
    }
}

// K1: dense conv1 (measured-best structure, R6/R14: 45.7us, VALU 57%, occ 50%,
// no spill). grid 1024 = b(4) x yp(16) x pq(16); block = 512 = 8 waves: wave w
// -> plane pq*4 + (w&3), c-half (w>>2); 4 blocks/CU -> 32 waves/CU (HW cap).
// Raw-x coalesced f32 loads, wave-uniform pre-scaled theta -> s_loads,
// unconditional clamped LUT gathers (border folded into per-lane clamp limit;
// invalid taps -> lut[0] ~ 0). Two parity accumulators. unroll 2 is the
// measured optimum: unroll 4 spills (R15), manual pipelines spill or lose
// (R10/R11/R13), int-path loses (R9).
__global__ __launch_bounds__(512, 8) void k1_conv1(
    const float* __restrict__ x, const float* __restrict__ th1s,
    const float* __restrict__ psc, const float* __restrict__ ls1,
    const float* __restrict__ lutg,
    float* __restrict__ rawb, float* __restrict__ sums1)
{
    __shared__ float lut[NLUT];
    __shared__ float part[256];
    {
        const float4* s = (const float4*)lutg;
        float4* d = (float4*)lut;
        for (int i = threadIdx.x; i < NLUT / 4; i += 512) d[i] = s[i];
    }
    __syncthreads();

    int blk = blockIdx.x;
    int pq = blk & 15;
    int yp = (blk >> 4) & 15;
    int b  = blk >> 8;
    int wv   = __builtin_amdgcn_readfirstlane((int)threadIdx.x >> 6);
    int lane = threadIdx.x & 63;
    int r = lane >> 5, xc = lane & 31;
    int y = yp * 2 + r;
    int p  = pq * 4 + (wv & 3);
    int c0 = (wv >> 2) * 32;

    // per-lane tap offsets (address-clamped) + clamp limit encoding validity
    int poff[9]; float lim[9];
    #pragma unroll
    for (int t = 0; t < 9; ++t) {
        int ny = y + t / 3 - 1, nx = xc + t % 3 - 1;
        bool val = ((unsigned)ny < 32u) && ((unsigned)nx < 32u);
        int nyc = min(max(ny, 0), 31), nxc = min(max(nx, 0), 31);
        poff[t] = nyc * 32 + nxc;
        lim[t] = val ? BLIM : 0.0f;
    }

    const float* xb = x + b * 65536 + c0 * 1024;
    const float* tp = th1s + p * 576 + c0 * 9;
    float SC = psc[0] * INVH4;
    float acc0 = 0.f, acc1 = 0.f;

    #pragma unroll 2
    for (int c = 0; c < 32; ++c) {
        const float* xr = xb + c * 1024;
        float v[9];
        #pragma unroll
        for (int t = 0; t < 9; ++t) v[t] = xr[poff[t]];
        const float* tc = tp + c * 9;
        #pragma unroll
        for (int t = 0; t < 9; ++t) {
            float q = fmaf(v[t], SC, tc[t]);         // theta via SGPR
            q = fminf(fmaxf(q, 0.f), lim[t]);        // v_med3 (border folded)
            int qb = (int)q & ~3;                    // aligned byte offset
            float e = *(const float*)((const char*)lut + qb);
            if (t & 1) acc1 += e; else acc0 += e;
        }
    }
    float acc = acc0 + acc1;

    // combine c-halves: upper half deposits, lower half finalizes
    if (wv >= 4) part[(wv & 3) * 64 + lane] = acc;
    __syncthreads();
    if (wv < 4) {
        acc += part[wv * 64 + lane];
        float r0 = ls1[0] * acc;
        rawb[((b * 64 + p) * 32 + y) * 32 + xc] = r0;

        float s0 = r0, q0 = r0 * r0;
        for (int s = 32; s > 0; s >>= 1) {
            s0 += __shfl_xor(s0, s);
            q0 += __shfl_xor(q0, s);
        }
        if (lane == 0) {
            atomicAdd(&sums1[p], s0);
            atomicAdd(&sums1[64 + p], q0);
        }
    }
}

// K3: BN1 apply in place on rawb (=d_out) + activity masks via atomicOr (masks
// region zeroed by k0). float4.
__global__ __launch_bounds__(256) void k3_bn1mask(float* __restrict__ v2,
    const float* __restrict__ sums1, const float* __restrict__ g1,
    const float* __restrict__ b1, unsigned long long* __restrict__ masks)
{
    int i4 = blockIdx.x * 256 + threadIdx.x;       // 0..65535
    int idx = i4 * 4;
    int c = (idx >> 10) & 63;
    int b = idx >> 16;
    float m   = sums1[c] * (1.f / 4096.f);
    float var = sums1[64 + c] * (1.f / 4096.f) - m * m;
    var = fmaxf(var, 0.f);
    float rstd = rsqrtf(var + 1e-5f);
    float sc = rstd * g1[c];
    float sh = b1[c] - m * sc;
    float4 v = ((float4*)v2)[i4];
    v.x = fmaf(v.x, sc, sh); v.y = fmaf(v.y, sc, sh);
    v.z = fmaf(v.z, sc, sh); v.w = fmaf(v.w, sc, sh);
    ((float4*)v2)[i4] = v;
    unsigned long long bit = 1ull << c;
    float vv[4] = {v.x, v.y, v.z, v.w};
    #pragma unroll
    for (int k = 0; k < 4; ++k) {
        if (vv[k] > WLO && vv[k] < WHI)
            atomicOr(&masks[b * 1024 + ((idx + k) & 1023)], bit);
    }
}

// K4: sparse conv2. grid 1024, wave per pixel, lane = output plane. Exact f32 eval.
__global__ __launch_bounds__(256) void k4_conv2(const float* __restrict__ v2,
    const float* __restrict__ th2t, const unsigned long long* __restrict__ masks,
    const float* __restrict__ ls2, __half* __restrict__ c2h, float* __restrict__ sums2)
{
    int wv = __builtin_amdgcn_readfirstlane((int)threadIdx.x >> 6);
    int lane = threadIdx.x & 63;
    int P = blockIdx.x * 4 + wv;                   // 0..4095
    int b = P >> 10, rem = P & 1023;
    int y = rem >> 5, xq2 = rem & 31;
    float l2 = ls2[0];
    const float inv_nvt = (float)(1.0 / (1.5 * 0.026));
    float acc = 0.f;

    #pragma unroll
    for (int j = 0; j < 9; ++j) {
        int ny = y + j / 3 - 1, nx = xq2 + j % 3 - 1;
        if ((unsigned)ny < 32u && (unsigned)nx < 32u) {
            int tp = ny * 32 + nx;
            unsigned long long mk = masks[b * 1024 + tp];
            while (mk) {
                int c = __ffsll((long long)mk) - 1;
                mk &= mk - 1;
                float v  = v2[(b * 64 + c) * 1024 + tp];            // uniform
                float th = th2t[(c * 9 + j) * 64 + lane];           // coalesced
                float d = v - th;
                if (d > BAND_LO && d < BAND_HI) {
                    float a1 = fminf(fmaxf(d * inv_nvt, -30.f), 30.f);
                    float a2 = fminf(fmaxf((d - 0.1f) * inv_nvt, -30.f), 30.f);
                    float s1 = __logf(1.f + __expf(a1));
                    float s2 = __logf(1.f + __expf(a2));
                    acc += (s1 * s1 - s2 * s2);
                }
            }
        }
    }
    float r2 = 0.0005625f * l2 * acc;
    c2h[((b * 64 + lane) * 32 + y) * 32 + xq2] = __float2half(r2); // channel-major

    __shared__ float ss[256], sq[256];
    ss[threadIdx.x] = r2; sq[threadIdx.x] = r2 * r2;
    __syncthreads();
    if (threadIdx.x < 64) {
        float a  = ss[threadIdx.x] + ss[threadIdx.x + 64] + ss[threadIdx.x + 128] + ss[threadIdx.x + 192];
        float qq = sq[threadIdx.x] + sq[threadIdx.x + 64] + sq[threadIdx.x + 128] + sq[threadIdx.x + 192];
        atomicAdd(&sums2[threadIdx.x], a);
        atomicAdd(&sums2[64 + threadIdx.x], qq);
    }
}

// K6: BN2 apply + residual, c2h -> d_out. float4 on x/out, half2 on c2.
__global__ __launch_bounds__(256) void k6_final(float* __restrict__ out,
    const float* __restrict__ x, const __half* __restrict__ c2h,
    const float* __restrict__ sums2,
    const float* __restrict__ g2, const float* __restrict__ b2)
{
    int i4 = blockIdx.x * 256 + threadIdx.x;       // 0..65535
    int idx = i4 * 4;
    int p = (idx >> 10) & 63;
    float m   = sums2[p] * (1.f / 4096.f);
    float var = sums2[64 + p] * (1.f / 4096.f) - m * m;
    var = fmaxf(var, 0.f);
    float rstd = rsqrtf(var + 1e-5f);
    float sc = rstd * g2[p];
    float sh = b2[p] - m * sc;
    const __half2* ch = (const __half2*)c2h;
    __half2 h0 = ch[i4 * 2], h1 = ch[i4 * 2 + 1];
    float2 c01 = __half22float2(h0), c23 = __half22float2(h1);
    float4 xv = ((const float4*)x)[i4];
    float4 o;
    o.x = fmaf(c01.x, sc, sh) + xv.x;
    o.y = fmaf(c01.y, sc, sh) + xv.y;
    o.z = fmaf(c23.x, sc, sh) + xv.z;
    o.w = fmaf(c23.y, sc, sh) + xv.w;
    ((float4*)out)[i4] = o;
}

extern "C" void kernel_launch(void* const* d_in, const int* in_sizes, int n_in,
                              void* d_out, int out_size, void* d_ws, size_t ws_size,
                              hipStream_t stream)
{
    const float* x   = (const float*)d_in[0];
    const float* th1 = (const float*)d_in[1];
    const float* th2 = (const float*)d_in[2];
    const float* psc = (const float*)d_in[3];
    const float* psh = (const float*)d_in[4];
    const float* l1  = (const float*)d_in[5];
    const float* l2  = (const float*)d_in[6];
    const float* g1  = (const float*)d_in[7];
    const float* b1  = (const float*)d_in[8];
    const float* g2  = (const float*)d_in[9];
    const float* b2  = (const float*)d_in[10];
    float* out = (float*)d_out;
    char* ws = (char*)d_ws;
    if (ws_size < (size_t)WS_TOTAL) return;  // defensive: leave output poisoned

    float*  lutg = (float*)(ws + WS_LUT);
    float*  th2t = (float*)(ws + WS_TH2T);
    float*  th1s = (float*)(ws + WS_TH1S);
    __half* c2h  = (__half*)(ws + WS_C2H);
    unsigned long long* masks = (unsigned long long*)(ws + WS_MASK);  // zeroed by k0
    float*  sums1 = (float*)(ws + WS_SUMS1);
    float*  sums2 = (float*)(ws + WS_SUMS2);
    unsigned* zerow = (unsigned*)(ws + WS_MASK);  // zero phase covers masks+sums

    float* rawb = out;   // conv1 raw / BN1-applied activations live in d_out

    k0_prep   <<<218,  256, 0, stream>>>(th1, th2, psh, lutg, th2t, th1s, zerow);
    k1_conv1  <<<1024, 512, 0, stream>>>(x, th1s, psc, l1, lutg, rawb, sums1);
    k3_bn1mask<<<256,  256, 0, stream>>>(rawb, sums1, g1, b1, masks);
    k4_conv2  <<<1024, 256, 0, stream>>>(rawb, th2t, masks, l2, c2h, sums2);
    k6_final  <<<256,  256, 0, stream>>>(out, x, c2h, sums2, g2, b2);
}